// Round 15
// baseline (410.049 us; speedup 1.0000x reference)
//
#include <hip/hip_runtime.h>
#include <stdint.h>

// Depthwise causal conv via MFMA Toeplitz, f16 compute, f32 LDS, gll-pipelined.
//   y[p,q] = sum_{r,s} w[r,s] * xm[p+r-5, q+s-5], xm/out causally masked.
// A = Toeplitz weights (m = local q), B = x tile (n = local p).
// Block marches NT=8 32-row subtiles down one 64-col column, double-buffered:
//   loop: __syncthreads() (drains prefetch) | issue global_load_lds(t+1)
//         | compute(t) [MFMA hides the DMA] | ...
// global_load_lds prefetch carries ZERO registers across compute (the r3/r7/
// r10 spill trap is structurally impossible); plain __syncthreads only.
// f32 in LDS (gll can't convert); f32->f16 via v_cvt_pkrtz at fragment read.
// N=2, C=16, H=W=2048.

#define HDIM 2048
#define WDIM 2048
#define CH   16
#define NT   8              // 32-row subtiles per block (256-row segment)
#define PITCHF 84           // f32 per LDS row (336B): j16-lanes cover 32 banks
#define TROWS  37           // 32 + 5 halo rows
#define GRR    21           // 16B granules per LDS row (84 floats)
#define NSL    (TROWS*GRR)  // 777

typedef float    f32x4 __attribute__((ext_vector_type(4)));
typedef __fp16   h16x2 __attribute__((ext_vector_type(2)));
typedef _Float16 f16x8 __attribute__((ext_vector_type(8)));

typedef const __attribute__((address_space(1))) uint32_t* gptr_t;
typedef __attribute__((address_space(3))) uint32_t* lptr_t;

static __device__ __forceinline__ f16x8 pack8(f32x4 a, f32x4 b) {
  union { h16x2 h[4]; f16x8 v; } u;
  u.h[0] = __builtin_amdgcn_cvt_pkrtz(a[0], a[1]);
  u.h[1] = __builtin_amdgcn_cvt_pkrtz(a[2], a[3]);
  u.h[2] = __builtin_amdgcn_cvt_pkrtz(b[0], b[1]);
  u.h[3] = __builtin_amdgcn_cvt_pkrtz(b[2], b[3]);
  return u.v;
}

__global__ __launch_bounds__(256, 6)
void dwconv_mfma(const float* __restrict__ x, const float* __restrict__ wgt,
                 float* __restrict__ out) {
  const int bx = blockIdx.x, seg = blockIdx.y, plane = blockIdx.z;
  const int q0 = bx * 64;
  const int tid = threadIdx.x;
  const size_t pb = (size_t)plane * HDIM * WDIM;
  const float* __restrict__ xp = x + pb;
  float* __restrict__ op = out + pb;

  __shared__ __attribute__((aligned(16))) float sx[2][TROWS * PITCHF];  // 24.8KB

  // subtile class: 0 = strictly-upper (zeros), 1 = pure (gll), 2 = masked.
  // pure: staged rows [p0-5,p0+31], cols [q0-8,q0+76) incl pad granule, all
  // in-bounds (bx in [1,30]) and causal (q0+75 <= p0-5).
  auto tclass = [&](int p0) -> int {
    if (p0 + 31 < q0) return 0;
    return ((bx >= 1) && (bx <= 30) && (p0 >= q0 + 80)) ? 1 : 2;
  };

  auto stage = [&](int p0, float* buf) {
    if (tclass(p0) == 1) {
      // Async DMA, linear LDS dest (prefix-contiguous lane guard).
#pragma unroll
      for (int j = 0; j < 4; ++j) {
        int slot = j * 256 + tid;
        if (slot < NSL) {
          int row = slot / GRR;
          int c4 = slot - row * GRR;
          const float* ga =
              xp + (size_t)(p0 - 5 + row) * WDIM + (q0 - 8 + 4 * c4);
          __builtin_amdgcn_global_load_lds((gptr_t)ga, (lptr_t)(buf + slot * 4),
                                           16, 0, 0);
        }
      }
    } else {  // masked: reg roundtrip, fully predicated (transient regs only)
#pragma unroll
      for (int j = 0; j < 4; ++j) {
        int slot = j * 256 + tid;
        if (slot < NSL) {
          int row = slot / GRR;
          int c4 = slot - row * GRR;
          int ih = p0 - 5 + row;
          int cb = q0 - 8 + 4 * c4;
          float4 v = make_float4(0.f, 0.f, 0.f, 0.f);
          if (ih >= 0) {  // ih <= p0+31 <= 2047 always
            bool fullv = (cb >= 0) && (cb + 3 <= ih) && (cb + 3 < WDIM);
            if (fullv) {
              v = *(const float4*)(xp + (size_t)ih * WDIM + cb);
            } else {
              float* vv = &v.x;
#pragma unroll
              for (int e = 0; e < 4; ++e) {
                int iw = cb + e;
                if (iw >= 0 && iw < WDIM && iw <= ih)
                  vv[e] = xp[(size_t)ih * WDIM + iw];
              }
            }
          }
          *(float4*)(buf + slot * 4) = v;
        }
      }
    }
  };

  // ---- Toeplitz A-fragments: lane holds A[m=j16, k=8wk+i] = w[r, k-m-3] ----
  const int lane = tid & 63;
  const int j16 = lane & 15;   // A: m / B: n / D: col
  const int wk  = lane >> 4;   // k-octet / D row quartet
  const int wid = tid >> 6;
  const int h   = wid & 1;     // 16-row half of subtile
  const int qh  = wid >> 1;    // 32-col half
  const float* __restrict__ wcp = wgt + (plane & (CH - 1)) * 66;
  f16x8 aw[6];
#pragma unroll
  for (int r = 0; r < 6; ++r) {
#pragma unroll
    for (int i = 0; i < 8; ++i) {
      int d = 8 * wk + i - j16 - 3;  // tap index s
      aw[r][i] = (_Float16)((d >= 0 && d <= 10) ? wcp[r * 11 + d] : 0.f);
    }
  }

  // ---- Prologue: stage subtile 0 ----
  {
    const int p00 = seg * (NT * 32);
    if (tclass(p00) != 0) stage(p00, sx[0]);
  }

  // ---- Pipelined march down the column ----
#pragma unroll 1
  for (int t = 0; t < NT; ++t) {
    const int p0 = seg * (NT * 32) + t * 32;

    __syncthreads();  // drains stage(t) DMA (issued last iter / prologue)

    // Issue prefetch for t+1 FIRST: its HBM latency hides under compute(t).
    if (t + 1 < NT) {
      const int p0n = p0 + 32;
      if (tclass(p0n) != 0) stage(p0n, sx[(t + 1) & 1]);
    }

    const int cls = tclass(p0);
    if (cls == 0) {
      // strictly-upper subtile: zeros (2 float4 per thread)
      const float4 z = make_float4(0.f, 0.f, 0.f, 0.f);
#pragma unroll
      for (int i = 0; i < 2; ++i) {
        int idx = i * 256 + tid;
        int row = idx >> 4, c4 = idx & 15;  // 32 rows x 16 float4
        *(float4*)(op + (size_t)(p0 + row) * WDIM + q0 + 4 * c4) = z;
      }
    } else {
      const float* __restrict__ lb = sx[t & 1];
      f32x4 acc[2];
      acc[0] = (f32x4){0.f, 0.f, 0.f, 0.f};
      acc[1] = (f32x4){0.f, 0.f, 0.f, 0.f};
#pragma unroll
      for (int qt = 0; qt < 2; ++qt) {
#pragma unroll
        for (int r = 0; r < 6; ++r) {
          // B[k=8wk+i, n=j16] = x_sub[16h + j16 + r, 32qh + 16qt + 8wk + i]
          int off = (16 * h + j16 + r) * PITCHF + 32 * qh + 16 * qt + 8 * wk;
          f32x4 lo = *(const f32x4*)&lb[off];
          f32x4 hi = *(const f32x4*)&lb[off + 4];
          acc[qt] = __builtin_amdgcn_mfma_f32_16x16x32_f16(aw[r], pack8(lo, hi),
                                                           acc[qt], 0, 0, 0);
        }
      }
      // D: col = n = j16 (p-axis), row = m = 4wk+reg (q-axis) -> float4 store
      const int p = p0 + 16 * h + j16;
      const bool needmask = (q0 + 63 > p0);
#pragma unroll
      for (int qt = 0; qt < 2; ++qt) {
        const int q = q0 + 32 * qh + 16 * qt + 4 * wk;
        f32x4 a = acc[qt];
        if (needmask) {
#pragma unroll
          for (int reg = 0; reg < 4; ++reg)
            if (q + reg > p) a[reg] = 0.f;
        }
        *(float4*)(op + (size_t)p * WDIM + q) =
            make_float4(a[0], a[1], a[2], a[3]);
      }
    }
  }
}

extern "C" void kernel_launch(void* const* d_in, const int* in_sizes, int n_in,
                              void* d_out, int out_size, void* d_ws, size_t ws_size,
                              hipStream_t stream) {
  const float* x   = (const float*)d_in[0];
  const float* wgt = (const float*)d_in[1];
  float* out       = (float*)d_out;
  dim3 grid(WDIM / 64, HDIM / (32 * NT), 2 * CH);  // (32, 8, 32)
  dwconv_mfma<<<grid, dim3(256), 0, stream>>>(x, wgt, out);
}